// Round 9
// baseline (202.791 us; speedup 1.0000x reference)
//
#include <hip/hip_runtime.h>
#include <hip/hip_bf16.h>

#define NB 8192     // batch
#define IC 32       // input capsules
#define ID 288      // input dims (K)
#define OD16 160    // OUT_CAPS*OUT_DIMS (N)

typedef __attribute__((ext_vector_type(8))) short bf16x8;
typedef __attribute__((ext_vector_type(4))) float f32x4;

__device__ __forceinline__ unsigned short f2bf(float f) {
    unsigned int u = __builtin_bit_cast(unsigned int, f);
    u = u + 0x7fffu + ((u >> 16) & 1u);   // round-to-nearest-even
    return (unsigned short)(u >> 16);
}
__device__ __forceinline__ float bf2f(unsigned short h) {
    return __builtin_bit_cast(float, ((unsigned int)h) << 16);
}
// 8 floats -> 8 bf16 via v_cvt_pk_bf16_f32 (compiler-generated)
__device__ __forceinline__ bf16x8 cvt_bf8(const f32x4& a, const f32x4& b) {
    union { __hip_bfloat162 h[4]; bf16x8 v; } u;
    u.h[0] = __float22bfloat162_rn(make_float2(a[0], a[1]));
    u.h[1] = __float22bfloat162_rn(make_float2(a[2], a[3]));
    u.h[2] = __float22bfloat162_rn(make_float2(b[0], b[1]));
    u.h[3] = __float22bfloat162_rn(make_float2(b[2], b[3]));
    return u.v;
}

__device__ __forceinline__ void gld_lds16(const void* g, void* l) {
    __builtin_amdgcn_global_load_lds((const __attribute__((address_space(1))) unsigned int*)g,
                                     (__attribute__((address_space(3))) unsigned int*)l, 16, 0, 0);
}

// ---------------------------------------------------------------------------
// prep: one block per (c, s). LDS-transpose W's [kw x 160] f32 tile to bf16,
// emit B image Bimg[c][kc=9][n=160][4 slots of 16B]: 64B rows, slot s holds
// granule g = s ^ ((n>>1)&3) so a linear global_load_lds dest + slot-swizzled
// ds_read_b128 (2-way banks = free) reconstructs B. 288 = 9*32, no padding.
// Block 0 additionally zeros a_part[3][8][320].
// ---------------------------------------------------------------------------
__global__ __launch_bounds__(256) void prep_kernel(const float* __restrict__ W,
                                                   unsigned short* __restrict__ Bimg,
                                                   float* __restrict__ a_arr) {
    __shared__ short tile[160 * 72];   // row n: 64 k-shorts (+pad), 144B stride
    const int bx = blockIdx.x;
    const int c = bx / 5;
    const int s = bx - c * 5;
    const int t = threadIdx.x;
    if (bx == 0) {
        for (int i = t; i < 3 * 8 * 320; i += 256) a_arr[i] = 0.f;
    }
    const int kw = (s == 4) ? 32 : 64;
    const int nel = kw * 160;
    for (int idx = t; idx < nel; idx += 256) {
        int k = idx / 160;
        int n = idx - k * 160;
        tile[n * 72 + k] = (short)f2bf(W[((long)c * ID + s * 64 + k) * OD16 + n]);
    }
    __syncthreads();
    unsigned short* dst0 = Bimg + ((long)c * 9 + s * 2) * (160 * 32);
    const int nkc = (s == 4) ? 1 : 2;
    for (int kcl = 0; kcl < nkc; ++kcl) {
        unsigned short* dst = dst0 + kcl * (160 * 32);
        for (int p = t; p < 640; p += 256) {
            int n = p >> 2;
            int sl = p & 3;
            int g = sl ^ ((n >> 1) & 3);
            *(uint4*)(dst + p * 8) = *(const uint4*)&tile[n * 72 + kcl * 32 + g * 8];
        }
    }
}

// ---------------------------------------------------------------------------
// gemm: u_hat[c][b][od] = data[b][c][:] @ W[c][:][od], bf16 MFMA 16x16x32.
// FULL-K A staging for DRAM page locality: M=64 block, wave owns one 16-row
// m-frag; its 16 rows x 1152B K-slices are staged ONCE into a wave-private
// LDS region (19 x global_load_lds, per-lane source walks rows contiguously
// -> ~1152B per page activation instead of 9 x 128B). Row stride 1168B
// (==16 mod 128) -> conflict-free ds_read_b128 fragment reads, no swizzle.
// B: proven kc-granular image staging (2 x 10KB dbuf, slot swizzle,
// counted vmcnt(3), 2 barriers/kc). Grid (cc, bx): 32 cc-blocks of one bx
// in flight together -> full 36KB A-rows covered; Bimg[cc] pins to one XCD L2.
// LDS 96KB -> 1 block/CU; 100KB DMA outstanding/CU >> BW*latency (~10KB).
// ---------------------------------------------------------------------------
__global__ __launch_bounds__(256) void gemm_kernel(const float* __restrict__ data,
                                                   const unsigned short* __restrict__ Bimg,
                                                   unsigned short* __restrict__ uhat) {
    __shared__ alignas(16) char lds[98304];   // [0,77824): A (4x19456), then B (2x10240)
    char* const Alds = lds;
    char* const Blds = lds + 77824;
    const int tid = threadIdx.x;
    const int lane = tid & 63;
    const int w = tid >> 6;
    const int q = lane >> 4;     // 0..3
    const int r = lane & 15;
    const int cc = blockIdx.x;
    const int b0 = blockIdx.y * 64;

    const float* Abase = data + (long)(b0 + w * 16) * (IC * ID) + cc * ID;
    const unsigned short* Bc = Bimg + (long)cc * (9 * 160 * 32);

    f32x4 acc[10];
    #pragma unroll
    for (int j = 0; j < 10; ++j) acc[j] = (f32x4){0.f, 0.f, 0.f, 0.f};

    // ---- stage A full-K: 16 rows x 1168B padded region, linear LDS dest,
    //      per-lane source = (row = n/73, granule = n%73 clamped) of 16B units.
    {
        char* Adst = Alds + w * 19456;
        #pragma unroll
        for (int j = 0; j < 19; ++j) {
            unsigned n = j * 64 + lane;
            unsigned rw = (n * 919300u) >> 26;        // exact n/73 for n<=1215
            unsigned cg = n - rw * 73;
            rw = (rw > 15u) ? 15u : rw;
            cg = (cg > 71u) ? 71u : cg;               // clamp into 1152B slice
            gld_lds16(Abase + (long)rw * (IC * ID) + cg * 4, Adst + j * 1024);
        }
    }
    auto issueB = [&](int buf, int kc) {   // 3 DMA ops/wave (3rd half-masked)
        const unsigned short* src = Bc + kc * (160 * 32) + (w * 160 + lane) * 8;
        char* dst = Blds + buf * 10240 + w * 2560;
        gld_lds16(src, dst);
        gld_lds16(src + 64 * 8, dst + 1024);
        if (lane < 32) gld_lds16(src + 128 * 8, dst + 2048);
    };

#define COMPUTE(KC)                                                            \
    {                                                                          \
        const char* Ab = Alds + w * 19456;                                     \
        const char* Bb = Blds + ((KC) & 1) * 10240;                            \
        const int slot = q ^ ((r >> 1) & 3);                                   \
        bf16x8 bfr[10];                                                        \
        _Pragma("unroll")                                                      \
        for (int nf = 0; nf < 10; ++nf)                                        \
            bfr[nf] = *(const bf16x8*)(Bb + (nf * 16 + r) * 64 + slot * 16);   \
        f32x4 alo = *(const f32x4*)(Ab + r * 1168 + (KC) * 128 + q * 32);      \
        f32x4 ahi = *(const f32x4*)(Ab + r * 1168 + (KC) * 128 + q * 32 + 16); \
        bf16x8 af = cvt_bf8(alo, ahi);                                         \
        _Pragma("unroll")                                                      \
        for (int nf = 0; nf < 10; ++nf)                                        \
            acc[nf] = __builtin_amdgcn_mfma_f32_16x16x32_bf16(af, bfr[nf], acc[nf], 0, 0, 0); \
    }

#define WAITV(N)  { asm volatile("s_waitcnt vmcnt(" N ")" ::: "memory");       \
                    __builtin_amdgcn_sched_barrier(0); }
#define BAR()     { __builtin_amdgcn_s_barrier(); }

    issueB(0, 0); issueB(1, 1);   // outstanding: A(19)+B0(3)+B1(3)=25

    WAITV("3") BAR() COMPUTE(0) BAR() issueB(0, 2);
    WAITV("3") BAR() COMPUTE(1) BAR() issueB(1, 3);
    WAITV("3") BAR() COMPUTE(2) BAR() issueB(0, 4);
    WAITV("3") BAR() COMPUTE(3) BAR() issueB(1, 5);
    WAITV("3") BAR() COMPUTE(4) BAR() issueB(0, 6);
    WAITV("3") BAR() COMPUTE(5) BAR() issueB(1, 7);
    WAITV("3") BAR() COMPUTE(6) BAR() issueB(0, 8);
    WAITV("3") BAR() COMPUTE(7) BAR()
    WAITV("0") BAR() COMPUTE(8)

#undef COMPUTE
#undef WAITV
#undef BAR

    // epilogue: C/D layout col=lane&15 (N), row=q*4+reg (M). Stage 64x160
    // bf16 tile (stride 168) through dead A LDS, contiguous 16B stores.
    __syncthreads();
    short* eb = (short*)lds;   // [64][168] shorts = 21504B
    #pragma unroll
    for (int rr = 0; rr < 4; ++rr) {
        const int m = w * 16 + (q << 2) + rr;
        #pragma unroll
        for (int nf = 0; nf < 10; ++nf)
            eb[m * 168 + nf * 16 + r] = (short)f2bf(acc[nf][rr]);
    }
    __syncthreads();
    unsigned short* dstc = uhat + ((long)cc * NB + b0) * 160;
    #pragma unroll
    for (int j = 0; j < 5; ++j) {
        const int chunk = j * 256 + tid;        // 1280 uint4
        const int row = chunk / 20;
        const int p = chunk - row * 20;
        *(uint4*)(dstc + (long)row * 160 + p * 8) = *(const uint4*)(eb + row * 168 + p * 8);
    }
}

// ---------------------------------------------------------------------------
// route: one wave per batch row, grid 2048x256. uhat layout [i][b][od]
// (plane stride PL). Softmax from 8-way-spread a partials; agreement u
// fragments preloaded to regs (overlap v-phase); v via tiny LDS; block-
// reduced a partials -> 320 atomics/block onto a_out[blockIdx&7].
// ---------------------------------------------------------------------------
template <int COMPUTE_A, int WRITE_V>
__global__ __launch_bounds__(256) void route_kernel(const unsigned short* __restrict__ uhat,
                                                    const float* __restrict__ a_all,  // [n_prev][8][320]
                                                    int n_prev,
                                                    float* __restrict__ a_out,        // [8][320]
                                                    float* __restrict__ v_out) {
    constexpr long PL = (long)NB * 160;   // i-plane stride (shorts)
    __shared__ float c_sh[320];
    __shared__ float v_lds[4][160];
    __shared__ float a_sh[4][320];
    const int tid = threadIdx.x;
    // --- softmax over input capsules (groups of 32, lane-aligned) ---
    for (int base = 0; base < 320; base += 256) {
        int t = base + tid;
        if (t < 320) {
            float bv = 0.f;
            for (int j = 0; j < n_prev * 8; ++j) bv += a_all[j * 320 + t];
            bv *= (1.0f / 8192.0f);
            float m = bv;
            #pragma unroll
            for (int off = 1; off < 32; off <<= 1) m = fmaxf(m, __shfl_xor(m, off));
            float e = __expf(bv - m);
            float ssum = e;
            #pragma unroll
            for (int off = 1; off < 32; off <<= 1) ssum += __shfl_xor(ssum, off);
            c_sh[t] = e / ssum;
        }
    }
    __syncthreads();

    const int w = tid >> 6;
    const int lane = tid & 63;
    const long row = (long)blockIdx.x * 4 + w;
    const unsigned short* __restrict__ u = uhat + row * 160;

    // preload agreement fragments: lane -> (i = lane&31, oo = (lane>>5)+2*s5)
    ushort4 ua[5][4];
    if (COMPUTE_A) {
        #pragma unroll
        for (int s5 = 0; s5 < 5; ++s5) {
            const int i = lane & 31;
            const int oo = (lane >> 5) + 2 * s5;
            #pragma unroll
            for (int d4 = 0; d4 < 4; ++d4)
                ua[s5][d4] = *(const ushort4*)(u + (long)i * PL + oo * 16 + d4 * 4);
        }
    }

    // v-phase: lanes 0..39, lane q owns od-quad q
    if (lane < 40) {
        const int q = lane;
        const int o = q >> 2;
        float4 sv = {0.f, 0.f, 0.f, 0.f};
        #pragma unroll 8
        for (int i = 0; i < 32; ++i) {
            ushort4 uu = *(const ushort4*)(u + (long)i * PL + q * 4);
            float ci = c_sh[o * 32 + i];
            sv.x += ci * bf2f(uu.x);
            sv.y += ci * bf2f(uu.y);
            sv.z += ci * bf2f(uu.z);
            sv.w += ci * bf2f(uu.w);
        }
        if (WRITE_V) *(float4*)(v_out + row * 160 + q * 4) = sv;
        if (COMPUTE_A) *(float4*)(&v_lds[w][q * 4]) = sv;
    }

    if (COMPUTE_A) {
        asm volatile("s_waitcnt lgkmcnt(0)" ::: "memory");  // v_lds visible wave-locally
        #pragma unroll
        for (int s5 = 0; s5 < 5; ++s5) {
            const int i = lane & 31;
            const int oo = (lane >> 5) + 2 * s5;
            const float* vp = &v_lds[w][oo * 16];
            float accv = 0.f;
            #pragma unroll
            for (int d4 = 0; d4 < 4; ++d4) {
                ushort4 uu = ua[s5][d4];
                float4 vv = *(const float4*)(vp + d4 * 4);
                float p0 = bf2f(uu.x) * vv.x;
                float p1 = bf2f(uu.y) * vv.y;
                float p2 = bf2f(uu.z) * vv.z;
                float p3 = bf2f(uu.w) * vv.w;
                accv += p0 * p0 + p1 * p1 + p2 * p2 + p3 * p3;
            }
            a_sh[w][oo * 32 + i] = sqrtf(accv);
        }
        __syncthreads();
        for (int t = tid; t < 320; t += 256) {
            float s4 = a_sh[0][t] + a_sh[1][t] + a_sh[2][t] + a_sh[3][t];
            atomicAdd(a_out + (blockIdx.x & 7) * 320 + t, s4);
        }
    }
}

// ---------------------------------------------------------------------------
extern "C" void kernel_launch(void* const* d_in, const int* in_sizes, int n_in,
                              void* d_out, int out_size, void* d_ws, size_t ws_size,
                              hipStream_t stream) {
    const float* data = (const float*)d_in[0];
    const float* W = (const float*)d_in[1];
    float* out = (float*)d_out;
    char* ws = (char*)d_ws;

    unsigned short* uhat = (unsigned short*)ws;           // [32][8192][160] bf16, 83,886,080 B
    size_t off = (size_t)NB * IC * OD16 * 2;
    unsigned short* Bimg = (unsigned short*)(ws + off);   // [32][9][160][32] bf16, 2,949,120 B
    off += 32L * 9 * 160 * 32 * 2;
    float* a_arr = (float*)(ws + off); off += 3 * 8 * 320 * 4;  // [it][8][320]

    hipLaunchKernelGGL(prep_kernel, dim3(160), dim3(256), 0, stream, W, Bimg, a_arr);
    hipLaunchKernelGGL(gemm_kernel, dim3(32, 128), dim3(256), 0, stream, data, Bimg, uhat);
    hipLaunchKernelGGL((route_kernel<1, 0>), dim3(2048), dim3(256), 0, stream,
                       uhat, a_arr, 0, a_arr + 0 * 2560, out);
    hipLaunchKernelGGL((route_kernel<1, 0>), dim3(2048), dim3(256), 0, stream,
                       uhat, a_arr, 1, a_arr + 1 * 2560, out);
    hipLaunchKernelGGL((route_kernel<0, 1>), dim3(2048), dim3(256), 0, stream,
                       uhat, a_arr, 2, a_arr + 2 * 2560, out);
}

// Round 10
// 165.635 us; speedup vs baseline: 1.2243x; 1.2243x over previous
//
#include <hip/hip_runtime.h>
#include <hip/hip_bf16.h>

#define NB 8192     // batch
#define IC 32       // input capsules
#define ID 288      // input dims (K)
#define OD16 160    // OUT_CAPS*OUT_DIMS (N)

typedef __attribute__((ext_vector_type(8))) short bf16x8;
typedef __attribute__((ext_vector_type(4))) float f32x4;

__device__ __forceinline__ unsigned short f2bf(float f) {
    unsigned int u = __builtin_bit_cast(unsigned int, f);
    u = u + 0x7fffu + ((u >> 16) & 1u);   // round-to-nearest-even
    return (unsigned short)(u >> 16);
}
__device__ __forceinline__ float bf2f(unsigned short h) {
    return __builtin_bit_cast(float, ((unsigned int)h) << 16);
}
// 8 floats -> 8 bf16 via v_cvt_pk_bf16_f32 (compiler-generated)
__device__ __forceinline__ bf16x8 cvt_bf8(const f32x4& a, const f32x4& b) {
    union { __hip_bfloat162 h[4]; bf16x8 v; } u;
    u.h[0] = __float22bfloat162_rn(make_float2(a[0], a[1]));
    u.h[1] = __float22bfloat162_rn(make_float2(a[2], a[3]));
    u.h[2] = __float22bfloat162_rn(make_float2(b[0], b[1]));
    u.h[3] = __float22bfloat162_rn(make_float2(b[2], b[3]));
    return u.v;
}

__device__ __forceinline__ void gld_lds16(const void* g, void* l) {
    __builtin_amdgcn_global_load_lds((const __attribute__((address_space(1))) unsigned int*)g,
                                     (__attribute__((address_space(3))) unsigned int*)l, 16, 0, 0);
}

// ---------------------------------------------------------------------------
// prep: one block per (c, s). LDS-transpose W's [kw x 160] f32 tile to bf16,
// emit B image Bimg[c][kc=9][n=160][4 slots of 16B]: 64B rows, slot s holds
// granule g = s ^ ((n>>1)&3) so a linear global_load_lds dest + slot-swizzled
// ds_read_b128 (2-way banks = free) reconstructs B. 288 = 9*32, no padding.
// Block 0 additionally zeros a_part[3][8][320].
// ---------------------------------------------------------------------------
__global__ __launch_bounds__(256) void prep_kernel(const float* __restrict__ W,
                                                   unsigned short* __restrict__ Bimg,
                                                   float* __restrict__ a_arr) {
    __shared__ short tile[160 * 72];   // row n: 64 k-shorts (+pad), 144B stride
    const int bx = blockIdx.x;
    const int c = bx / 5;
    const int s = bx - c * 5;
    const int t = threadIdx.x;
    if (bx == 0) {
        for (int i = t; i < 3 * 8 * 320; i += 256) a_arr[i] = 0.f;
    }
    const int kw = (s == 4) ? 32 : 64;
    const int nel = kw * 160;
    for (int idx = t; idx < nel; idx += 256) {
        int k = idx / 160;
        int n = idx - k * 160;
        tile[n * 72 + k] = (short)f2bf(W[((long)c * ID + s * 64 + k) * OD16 + n]);
    }
    __syncthreads();
    unsigned short* dst0 = Bimg + ((long)c * 9 + s * 2) * (160 * 32);
    const int nkc = (s == 4) ? 1 : 2;
    for (int kcl = 0; kcl < nkc; ++kcl) {
        unsigned short* dst = dst0 + kcl * (160 * 32);
        for (int p = t; p < 640; p += 256) {
            int n = p >> 2;
            int sl = p & 3;
            int g = sl ^ ((n >> 1) & 3);
            *(uint4*)(dst + p * 8) = *(const uint4*)&tile[n * 72 + kcl * 32 + g * 8];
        }
    }
}

// ---------------------------------------------------------------------------
// gemm: u_hat[c][b][od] = data[b][c][:] @ W[c][:][od], bf16 MFMA 16x16x32.
// R7 structure (best measured): A wave-private LDS dbuf via global_load_lds,
// B kc-granular image dbuf, counted vmcnt(7), 2 barriers/kc, 52KB LDS ->
// 3 blocks/CU. This round: grid flipped to cc-fastest (all 32 capsule
// slices of a batch row consumed while its DRAM pages are hot) + setprio(1)
// around the MFMA cluster (T5).
// ---------------------------------------------------------------------------
__global__ __launch_bounds__(256) void gemm_kernel(const float* __restrict__ data,
                                                   const unsigned short* __restrict__ Bimg,
                                                   unsigned short* __restrict__ uhat) {
    __shared__ alignas(16) char lds[53248];   // [0,32768): A, [32768,53248): B
    char* const Alds = lds;
    char* const Blds = lds + 32768;
    const int tid = threadIdx.x;
    const int lane = tid & 63;
    const int w = tid >> 6;
    const int q = lane >> 4;     // 0..3
    const int r = lane & 15;
    const int cc = blockIdx.x;            // cc fastest in dispatch order
    const int b0 = blockIdx.y * 128;

    // A DMA source: lane ℓ covers (row = w*32 + 8j + (ℓ>>3), chunk (ℓ&7)^((ℓ>>3)&7))
    const float* Ag = data + (long)(b0 + w * 32 + (lane >> 3)) * (IC * ID) + cc * ID
                      + ((lane & 7) ^ ((lane >> 3) & 7)) * 4;
    const unsigned short* Bc = Bimg + (long)cc * (9 * 160 * 32);

    f32x4 acc[2][10];
    #pragma unroll
    for (int i = 0; i < 2; ++i)
        #pragma unroll
        for (int j = 0; j < 10; ++j)
            acc[i][j] = (f32x4){0.f, 0.f, 0.f, 0.f};

    auto issueA = [&](int buf, int kc) {   // 4 DMA ops, wave-private slice
        char* dst = Alds + w * 8192 + buf * 4096;
        const float* src = Ag + kc * 32;
        #pragma unroll
        for (int j = 0; j < 4; ++j)
            gld_lds16(src + (long)j * 8 * (IC * ID), dst + j * 1024);
    };
    auto issueB = [&](int buf, int kc) {   // 3 DMA ops/wave (3rd half-masked)
        const unsigned short* src = Bc + kc * (160 * 32) + (w * 160 + lane) * 8;
        char* dst = Blds + buf * 10240 + w * 2560;
        gld_lds16(src, dst);
        gld_lds16(src + 64 * 8, dst + 1024);
        if (lane < 32) gld_lds16(src + 128 * 8, dst + 2048);
    };

#define COMPUTE(KC)                                                            \
    {                                                                          \
        const char* Ab = Alds + w * 8192 + ((KC) & 1) * 4096;                  \
        const char* Bb = Blds + ((KC) & 1) * 10240;                            \
        const int slot = q ^ ((r >> 1) & 3);                                   \
        bf16x8 bfr[10];                                                        \
        _Pragma("unroll")                                                      \
        for (int nf = 0; nf < 10; ++nf)                                        \
            bfr[nf] = *(const bf16x8*)(Bb + (nf * 16 + r) * 64 + slot * 16);   \
        bf16x8 af[2];                                                          \
        _Pragma("unroll")                                                      \
        for (int mf = 0; mf < 2; ++mf) {                                       \
            const int row = mf * 16 + r;                                       \
            const int c0 = (q * 2) ^ (r & 7);                                  \
            const int c1 = (q * 2 + 1) ^ (r & 7);                              \
            f32x4 alo = *(const f32x4*)(Ab + row * 128 + c0 * 16);             \
            f32x4 ahi = *(const f32x4*)(Ab + row * 128 + c1 * 16);             \
            af[mf] = cvt_bf8(alo, ahi);                                        \
        }                                                                      \
        __builtin_amdgcn_s_setprio(1);                                         \
        _Pragma("unroll")                                                      \
        for (int nf = 0; nf < 10; ++nf) {                                      \
            acc[0][nf] = __builtin_amdgcn_mfma_f32_16x16x32_bf16(af[0], bfr[nf], acc[0][nf], 0, 0, 0); \
            acc[1][nf] = __builtin_amdgcn_mfma_f32_16x16x32_bf16(af[1], bfr[nf], acc[1][nf], 0, 0, 0); \
        }                                                                      \
        __builtin_amdgcn_s_setprio(0);                                         \
    }

#define WAITV(N)  { asm volatile("s_waitcnt vmcnt(" N ")" ::: "memory");       \
                    __builtin_amdgcn_sched_barrier(0); }
#define BAR()     { __builtin_amdgcn_s_barrier(); }

    // prologue: FIFO A0,B0,A1,B1 (14 ops outstanding)
    issueA(0, 0); issueB(0, 0); issueA(1, 1); issueB(1, 1);
    WAITV("7") BAR() COMPUTE(0) BAR()
    issueA(0, 2); issueB(0, 2); WAITV("7") BAR() COMPUTE(1) BAR()
    issueA(1, 3); issueB(1, 3); WAITV("7") BAR() COMPUTE(2) BAR()
    issueA(0, 4); issueB(0, 4); WAITV("7") BAR() COMPUTE(3) BAR()
    issueA(1, 5); issueB(1, 5); WAITV("7") BAR() COMPUTE(4) BAR()
    issueA(0, 6); issueB(0, 6); WAITV("7") BAR() COMPUTE(5) BAR()
    issueA(1, 7); issueB(1, 7); WAITV("7") BAR() COMPUTE(6) BAR()
    issueA(0, 8); issueB(0, 8); WAITV("7") BAR() COMPUTE(7)
    WAITV("0") BAR() COMPUTE(8)

#undef COMPUTE
#undef WAITV
#undef BAR

    // epilogue: C/D layout col=lane&15 (N), row=q*4+reg (M). Stage 128x160
    // bf16 tile with padded stride 168 shorts (2-way banks on the scatter
    // writes), then contiguous 16B stores to uhat[c][b][od].
    __syncthreads();
    short* eb = (short*)lds;   // [128][168] shorts = 43008B
    #pragma unroll
    for (int mf = 0; mf < 2; ++mf)
        #pragma unroll
        for (int rr = 0; rr < 4; ++rr) {
            const int m = w * 32 + mf * 16 + (q << 2) + rr;
            #pragma unroll
            for (int nf = 0; nf < 10; ++nf)
                eb[m * 168 + nf * 16 + r] = (short)f2bf(acc[mf][nf][rr]);
        }
    __syncthreads();
    unsigned short* dstc = uhat + ((long)cc * NB + b0) * 160;
    #pragma unroll
    for (int j = 0; j < 10; ++j) {
        const int chunk = j * 256 + tid;        // 2560 uint4
        const int row = chunk / 20;
        const int p = chunk - row * 20;
        *(uint4*)(dstc + (long)row * 160 + p * 8) = *(const uint4*)(eb + row * 168 + p * 8);
    }
}

// ---------------------------------------------------------------------------
// route: one wave per batch row, grid 2048x256. uhat layout [i][b][od]
// (plane stride PL). Softmax from 8-way-spread a partials; agreement u
// fragments preloaded to regs (overlap v-phase); v via tiny LDS; block-
// reduced a partials -> 320 atomics/block onto a_out[blockIdx&7].
// ---------------------------------------------------------------------------
template <int COMPUTE_A, int WRITE_V>
__global__ __launch_bounds__(256) void route_kernel(const unsigned short* __restrict__ uhat,
                                                    const float* __restrict__ a_all,  // [n_prev][8][320]
                                                    int n_prev,
                                                    float* __restrict__ a_out,        // [8][320]
                                                    float* __restrict__ v_out) {
    constexpr long PL = (long)NB * 160;   // i-plane stride (shorts)
    __shared__ float c_sh[320];
    __shared__ float v_lds[4][160];
    __shared__ float a_sh[4][320];
    const int tid = threadIdx.x;
    // --- softmax over input capsules (groups of 32, lane-aligned) ---
    for (int base = 0; base < 320; base += 256) {
        int t = base + tid;
        if (t < 320) {
            float bv = 0.f;
            for (int j = 0; j < n_prev * 8; ++j) bv += a_all[j * 320 + t];
            bv *= (1.0f / 8192.0f);
            float m = bv;
            #pragma unroll
            for (int off = 1; off < 32; off <<= 1) m = fmaxf(m, __shfl_xor(m, off));
            float e = __expf(bv - m);
            float ssum = e;
            #pragma unroll
            for (int off = 1; off < 32; off <<= 1) ssum += __shfl_xor(ssum, off);
            c_sh[t] = e / ssum;
        }
    }
    __syncthreads();

    const int w = tid >> 6;
    const int lane = tid & 63;
    const long row = (long)blockIdx.x * 4 + w;
    const unsigned short* __restrict__ u = uhat + row * 160;

    // preload agreement fragments: lane -> (i = lane&31, oo = (lane>>5)+2*s5)
    ushort4 ua[5][4];
    if (COMPUTE_A) {
        #pragma unroll
        for (int s5 = 0; s5 < 5; ++s5) {
            const int i = lane & 31;
            const int oo = (lane >> 5) + 2 * s5;
            #pragma unroll
            for (int d4 = 0; d4 < 4; ++d4)
                ua[s5][d4] = *(const ushort4*)(u + (long)i * PL + oo * 16 + d4 * 4);
        }
    }

    // v-phase: lanes 0..39, lane q owns od-quad q
    if (lane < 40) {
        const int q = lane;
        const int o = q >> 2;
        float4 sv = {0.f, 0.f, 0.f, 0.f};
        #pragma unroll 8
        for (int i = 0; i < 32; ++i) {
            ushort4 uu = *(const ushort4*)(u + (long)i * PL + q * 4);
            float ci = c_sh[o * 32 + i];
            sv.x += ci * bf2f(uu.x);
            sv.y += ci * bf2f(uu.y);
            sv.z += ci * bf2f(uu.z);
            sv.w += ci * bf2f(uu.w);
        }
        if (WRITE_V) *(float4*)(v_out + row * 160 + q * 4) = sv;
        if (COMPUTE_A) *(float4*)(&v_lds[w][q * 4]) = sv;
    }

    if (COMPUTE_A) {
        asm volatile("s_waitcnt lgkmcnt(0)" ::: "memory");  // v_lds visible wave-locally
        #pragma unroll
        for (int s5 = 0; s5 < 5; ++s5) {
            const int i = lane & 31;
            const int oo = (lane >> 5) + 2 * s5;
            const float* vp = &v_lds[w][oo * 16];
            float accv = 0.f;
            #pragma unroll
            for (int d4 = 0; d4 < 4; ++d4) {
                ushort4 uu = ua[s5][d4];
                float4 vv = *(const float4*)(vp + d4 * 4);
                float p0 = bf2f(uu.x) * vv.x;
                float p1 = bf2f(uu.y) * vv.y;
                float p2 = bf2f(uu.z) * vv.z;
                float p3 = bf2f(uu.w) * vv.w;
                accv += p0 * p0 + p1 * p1 + p2 * p2 + p3 * p3;
            }
            a_sh[w][oo * 32 + i] = sqrtf(accv);
        }
        __syncthreads();
        for (int t = tid; t < 320; t += 256) {
            float s4 = a_sh[0][t] + a_sh[1][t] + a_sh[2][t] + a_sh[3][t];
            atomicAdd(a_out + (blockIdx.x & 7) * 320 + t, s4);
        }
    }
}

// ---------------------------------------------------------------------------
extern "C" void kernel_launch(void* const* d_in, const int* in_sizes, int n_in,
                              void* d_out, int out_size, void* d_ws, size_t ws_size,
                              hipStream_t stream) {
    const float* data = (const float*)d_in[0];
    const float* W = (const float*)d_in[1];
    float* out = (float*)d_out;
    char* ws = (char*)d_ws;

    unsigned short* uhat = (unsigned short*)ws;           // [32][8192][160] bf16, 83,886,080 B
    size_t off = (size_t)NB * IC * OD16 * 2;
    unsigned short* Bimg = (unsigned short*)(ws + off);   // [32][9][160][32] bf16, 2,949,120 B
    off += 32L * 9 * 160 * 32 * 2;
    float* a_arr = (float*)(ws + off); off += 3 * 8 * 320 * 4;  // [it][8][320]

    hipLaunchKernelGGL(prep_kernel, dim3(160), dim3(256), 0, stream, W, Bimg, a_arr);
    hipLaunchKernelGGL(gemm_kernel, dim3(32, 64), dim3(256), 0, stream, data, Bimg, uhat);
    hipLaunchKernelGGL((route_kernel<1, 0>), dim3(2048), dim3(256), 0, stream,
                       uhat, a_arr, 0, a_arr + 0 * 2560, out);
    hipLaunchKernelGGL((route_kernel<1, 0>), dim3(2048), dim3(256), 0, stream,
                       uhat, a_arr, 1, a_arr + 1 * 2560, out);
    hipLaunchKernelGGL((route_kernel<0, 1>), dim3(2048), dim3(256), 0, stream,
                       uhat, a_arr, 2, a_arr + 2 * 2560, out);
}